// Round 4
// baseline (201.925 us; speedup 1.0000x reference)
//
#include <hip/hip_runtime.h>
#include <stdint.h>

typedef unsigned long long u64;
typedef unsigned int u32;

#define T_STEPS 64
#define KDIM 784
#define N1 1024
#define NB 2048
#define N2 10

// ---------------- K0: W2 [10][1024] -> W2T [1024][12] (padded rows) ----------------
__global__ void k_w2t(const float* __restrict__ W2, float* __restrict__ W2T) {
    int j = blockIdx.x * blockDim.x + threadIdx.x;
    if (j >= N1) return;
    float r[12];
#pragma unroll
    for (int i = 0; i < 10; ++i) r[i] = W2[i * N1 + j];
    r[10] = 0.f; r[11] = 0.f;
#pragma unroll
    for (int i = 0; i < 12; ++i) W2T[j * 12 + i] = r[i];
}

// ---------------- K0b: tiled transposes X->Xt [784][2048], W1->W1t [784][1024] ----------------
// 32x32 tiles, 256 threads (32x8). Blocks [0,1600) do X, [1600,2400) do W1.
__global__ __launch_bounds__(256) void k_transpose2(
    const float* __restrict__ X, float* __restrict__ Xt,
    const float* __restrict__ W1, float* __restrict__ W1t)
{
    __shared__ float t[32][33];
    int b = blockIdx.x;
    const float* src; float* dst; int R;
    int tile_r, tile_c;
    if (b < 1600) { src = X;  dst = Xt;  R = NB; tile_r = b / 25; tile_c = b % 25; }
    else { b -= 1600; src = W1; dst = W1t; R = N1; tile_r = b / 25; tile_c = b % 25; }

    const int tx = threadIdx.x & 31, ty = threadIdx.x >> 5;
    const int r0 = tile_r << 5, c0 = tile_c << 5;

#pragma unroll
    for (int i = 0; i < 32; i += 8) {
        int c = c0 + tx;
        t[ty + i][tx] = (c < KDIM) ? src[(size_t)(r0 + ty + i) * KDIM + c] : 0.f;
    }
    __syncthreads();
#pragma unroll
    for (int i = 0; i < 32; i += 8) {
        int c = c0 + ty + i;
        if (c < KDIM) dst[(size_t)c * R + r0 + tx] = t[tx][ty + i];
    }
}

// ---------------- K1: c1 = X @ W1^T (fp32), LDS-free / barrier-free, fused LIF-1 ----------------
// 1 wave = 16 m-rows x 64 n-cols. lane = n. Per k: per-lane W1t load (coalesced) +
// 4x float4 wave-uniform Xt broadcast loads + 16 k-sequential v_fmac.
// Summation order k=0..783 strictly sequential per accumulator (bit-identical to prior run).
__global__ __launch_bounds__(256) void k_gemm_lif1(
    const float* __restrict__ Xt,    // [784][2048]
    const float* __restrict__ W1t,   // [784][1024]
    u64* __restrict__ bits)
{
    const int tid  = threadIdx.x;
    const int wv   = tid >> 6;
    const int lane = tid & 63;
    const int bx   = blockIdx.x;

    const int n0 = (bx & 15) << 6;                         // 0..960
    const int m0 = __builtin_amdgcn_readfirstlane(((bx >> 4) << 6) + (wv << 4)); // 0..2032, uniform

    const int n = n0 + lane;
    const float*  __restrict__ wrow = W1t + n;             // + k*1024 per step
    const float4* __restrict__ xrow = (const float4*)(Xt + m0);  // + k*512 per step (64B aligned)

    float acc[16];
#pragma unroll
    for (int i = 0; i < 16; ++i) acc[i] = 0.f;

#pragma unroll 4
    for (int k = 0; k < KDIM; ++k) {
        float a  = wrow[(size_t)k * N1];
        float4 x0 = xrow[(size_t)k * 512 + 0];
        float4 x1 = xrow[(size_t)k * 512 + 1];
        float4 x2 = xrow[(size_t)k * 512 + 2];
        float4 x3 = xrow[(size_t)k * 512 + 3];
        acc[ 0] = fmaf(a, x0.x, acc[ 0]); acc[ 1] = fmaf(a, x0.y, acc[ 1]);
        acc[ 2] = fmaf(a, x0.z, acc[ 2]); acc[ 3] = fmaf(a, x0.w, acc[ 3]);
        acc[ 4] = fmaf(a, x1.x, acc[ 4]); acc[ 5] = fmaf(a, x1.y, acc[ 5]);
        acc[ 6] = fmaf(a, x1.z, acc[ 6]); acc[ 7] = fmaf(a, x1.w, acc[ 7]);
        acc[ 8] = fmaf(a, x2.x, acc[ 8]); acc[ 9] = fmaf(a, x2.y, acc[ 9]);
        acc[10] = fmaf(a, x2.z, acc[10]); acc[11] = fmaf(a, x2.w, acc[11]);
        acc[12] = fmaf(a, x3.x, acc[12]); acc[13] = fmaf(a, x3.y, acc[13]);
        acc[14] = fmaf(a, x3.z, acc[14]); acc[15] = fmaf(a, x3.w, acc[15]);
    }

    // LIF layer 1: exact per-step recurrence, spikes recorded as 64-bit mask.
    // acc[u] is c1 for neuron (m0+u, n). Each thread: 16 independent trajectories.
    float v[16];
    u32 blo[16], bhi[16];
#pragma unroll
    for (int u = 0; u < 16; ++u) { v[u] = 0.f; blo[u] = 0u; bhi[u] = 0u; }
    for (int t = 0; t < 32; ++t) {
#pragma unroll
        for (int u = 0; u < 16; ++u) {
            v[u] += (acc[u] - v[u]) * 0.5f;         // v += (c - v)/tau, tau=2
            bool s = v[u] >= 1.0f;                  // spike(v - 1) == (v >= 1)
            blo[u] |= (s ? 1u : 0u) << t;
            v[u] = s ? 0.f : v[u];                  // hard reset
        }
    }
    for (int t = 0; t < 32; ++t) {
#pragma unroll
        for (int u = 0; u < 16; ++u) {
            v[u] += (acc[u] - v[u]) * 0.5f;
            bool s = v[u] >= 1.0f;
            bhi[u] |= (s ? 1u : 0u) << t;
            v[u] = s ? 0.f : v[u];
        }
    }

    u64* bp = bits + (size_t)m0 * N1 + n;   // store: lane=n contiguous -> coalesced 512B
#pragma unroll
    for (int u = 0; u < 16; ++u)
        bp[(size_t)u * N1] = ((u64)bhi[u] << 32) | (u64)blo[u];
}

// ---------------- K3: sparse c2 via compaction, LIF-2, write out ----------------
// 1 wave = 1 batch element; block = 4 waves = 4 consecutive batches.
__global__ __launch_bounds__(256) void k_lif2(
    const u64* __restrict__ bits, const float* __restrict__ W2T,
    float* __restrict__ out)
{
    __shared__ u64  masksS[4][N1];      // 32 KB
    __shared__ u32  idxS[4][N1];        // 16 KB
    __shared__ float c2S[4][64][12];    // 12 KB
    __shared__ float s2S[4][64][10];    // 10 KB   (total 70 KB -> 2 blocks/CU)

    const int tid  = threadIdx.x;
    const int w    = tid >> 6;      // wave = batch sub-index
    const int lane = tid & 63;
    const int b    = (blockIdx.x << 2) + w;

    const u64* row = bits + (size_t)b * N1;

    // ---- phase 1: scan + compact (coalesced, lane-parallel) ----
    int nact = 0;
#pragma unroll
    for (int it = 0; it < 16; ++it) {
        u64 m = row[lane + (it << 6)];
        u64 ball = __ballot(m != 0ULL);
        int pos = nact + __popcll(ball & ((1ULL << lane) - 1ULL));
        if (m != 0ULL) { masksS[w][pos] = m; idxS[w][pos] = lane + (it << 6); }
        nact += __popcll(ball);
    }

    // ---- phase 2: dense accumulation over active neurons; lane = t ----
    float acc[10];
#pragma unroll
    for (int i = 0; i < 10; ++i) acc[i] = 0.f;

#define LIF2_BODY(A)                                                      \
    {                                                                     \
        u64 m = masksS[w][(A)];                                           \
        int j = __builtin_amdgcn_readfirstlane((int)idxS[w][(A)]);        \
        float sf = (float)((m >> lane) & 1ULL);                           \
        const float* wr = W2T + j * 12;                                   \
        float4 w0 = *(const float4*)(wr);                                 \
        float4 w1 = *(const float4*)(wr + 4);                             \
        float2 w2 = *(const float2*)(wr + 8);                             \
        acc[0] += sf * w0.x; acc[1] += sf * w0.y;                         \
        acc[2] += sf * w0.z; acc[3] += sf * w0.w;                         \
        acc[4] += sf * w1.x; acc[5] += sf * w1.y;                         \
        acc[6] += sf * w1.z; acc[7] += sf * w1.w;                         \
        acc[8] += sf * w2.x; acc[9] += sf * w2.y;                         \
    }

    int a = 0;
    for (; a + 2 <= nact; a += 2) { LIF2_BODY(a); LIF2_BODY(a + 1); }
    if (a < nact) LIF2_BODY(a);
#undef LIF2_BODY

#pragma unroll
    for (int i = 0; i < 10; ++i) c2S[w][lane][i] = acc[i];
    __syncthreads();

    // ---- LIF layer 2: serial over t; 40 threads (4 batches x 10 channels) ----
    if (tid < 40) {
        const int w2 = tid / 10, i = tid % 10;
        float v2 = 0.f;
        for (int t = 0; t < 64; ++t) {
            float cc = c2S[w2][t][i];
            v2 += (cc - v2) * 0.5f;
            bool s = v2 >= 1.0f;
            s2S[w2][t][i] = s ? 1.f : 0.f;
            v2 = s ? 0.f : v2;
        }
    }
    __syncthreads();

    // ---- write out[t][b0..b0+3][0..9]: contiguous 160B per t ----
    const int b0 = blockIdx.x << 2;
    for (int idx = tid; idx < 64 * 40; idx += 256) {
        int t = idx / 40, r = idx % 40;
        out[(size_t)t * (NB * N2) + (size_t)b0 * N2 + r] = s2S[r / 10][t][r % 10];
    }
}

extern "C" void kernel_launch(void* const* d_in, const int* in_sizes, int n_in,
                              void* d_out, int out_size, void* d_ws, size_t ws_size,
                              hipStream_t stream) {
    const float* X  = (const float*)d_in[0];   // [2048, 784]
    const float* W1 = (const float*)d_in[1];   // [1024, 784]
    const float* W2 = (const float*)d_in[2];   // [10, 1024]
    float* out = (float*)d_out;                // [64, 2048, 10]

    char* ws = (char*)d_ws;
    u64*   bits = (u64*)ws;                                   // 16 MiB
    float* W2T  = (float*)(ws + (size_t)NB * N1 * 8);         // 48 KiB
    float* Xt   = (float*)(ws + (size_t)NB * N1 * 8 + 65536); // 784*2048*4 = 6.27 MiB
    float* W1t  = Xt + (size_t)KDIM * NB;                     // 784*1024*4 = 3.14 MiB

    k_w2t<<<dim3((N1 + 255) / 256), dim3(256), 0, stream>>>(W2, W2T);
    k_transpose2<<<dim3(2400), dim3(256), 0, stream>>>(X, Xt, W1, W1t);

    k_gemm_lif1<<<dim3(512), dim3(256), 0, stream>>>(Xt, W1t, bits);

    k_lif2<<<dim3(NB / 4), dim3(256), 0, stream>>>(bits, W2T, out);
}

// Round 5
// 164.209 us; speedup vs baseline: 1.2297x; 1.2297x over previous
//
#include <hip/hip_runtime.h>
#include <stdint.h>

typedef unsigned long long u64;
typedef unsigned int u32;

#define T_STEPS 64
#define KDIM 784
#define N1 1024
#define NB 2048
#define N2 10

// ---------------- K0: W2 [10][1024] -> W2T [1024][12] (padded rows) ----------------
__global__ void k_w2t(const float* __restrict__ W2, float* __restrict__ W2T) {
    int j = blockIdx.x * blockDim.x + threadIdx.x;
    if (j >= N1) return;
    float r[12];
#pragma unroll
    for (int i = 0; i < 10; ++i) r[i] = W2[i * N1 + j];
    r[10] = 0.f; r[11] = 0.f;
#pragma unroll
    for (int i = 0; i < 12; ++i) W2T[j * 12 + i] = r[i];
}

// ---------------- K0b: tiled transposes X->Xt [784][2048], W1->W1t [784][1024] ----------------
__global__ __launch_bounds__(256) void k_transpose2(
    const float* __restrict__ X, float* __restrict__ Xt,
    const float* __restrict__ W1, float* __restrict__ W1t)
{
    __shared__ float t[32][33];
    int b = blockIdx.x;
    const float* src; float* dst; int R;
    int tile_r, tile_c;
    if (b < 1600) { src = X;  dst = Xt;  R = NB; tile_r = b / 25; tile_c = b % 25; }
    else { b -= 1600; src = W1; dst = W1t; R = N1; tile_r = b / 25; tile_c = b % 25; }

    const int tx = threadIdx.x & 31, ty = threadIdx.x >> 5;
    const int r0 = tile_r << 5, c0 = tile_c << 5;

#pragma unroll
    for (int i = 0; i < 32; i += 8) {
        int c = c0 + tx;
        t[ty + i][tx] = (c < KDIM) ? src[(size_t)(r0 + ty + i) * KDIM + c] : 0.f;
    }
    __syncthreads();
#pragma unroll
    for (int i = 0; i < 32; i += 8) {
        int c = c0 + ty + i;
        if (c < KDIM) dst[(size_t)c * R + r0 + tx] = t[tx][ty + i];
    }
}

// ---------------- K1: c1 = X @ W1^T (fp32), glds-staged LDS dbuf, fused LIF-1 ----------------
// 64x64 block tile, 256 threads, 4x4 per thread. A/B tiles staged with
// global_load_lds width=16 (no VALU staging, no ds_write bank conflicts).
// 2-phase template: STAGE(t+1) -> compute(t) -> vmcnt(0)+s_barrier.
// FMA order identical to R3 (k ascending, sequential) -> c1 bit-identical.
#define NSTEP (KDIM / 16)   // 49

typedef const __attribute__((address_space(1))) void gas_void;
typedef __attribute__((address_space(3))) void las_void;

__global__ __launch_bounds__(256) void k_gemm_lif1(
    const float* __restrict__ Xt,    // [784][2048]
    const float* __restrict__ W1t,   // [784][1024]
    u64* __restrict__ bits)
{
    __shared__ __align__(16) float A2[2][16][64];   // 8 KB
    __shared__ __align__(16) float B2[2][16][64];   // 8 KB

    const int tid  = threadIdx.x;
    const int lane = tid & 63;
    const int tx   = tid & 15;             // n-group
    const int ty   = tid >> 4;             // m-group (0..15)
    const int bm   = blockIdx.y << 6;
    const int bn   = blockIdx.x << 6;

    // staging: wave w owns rows 4w..4w+3 of each 16x64 tile
    const int w4   = __builtin_amdgcn_readfirstlane((tid >> 6) << 2);
    const int srow = w4 + (lane >> 4);
    const int scol = (lane & 15) << 2;

    const float* gA = Xt  + (size_t)srow * NB + bm + scol;
    const float* gB = W1t + (size_t)srow * N1 + bn + scol;

#define STAGE(pp, t)                                                          \
    {                                                                         \
        __builtin_amdgcn_global_load_lds((gas_void*)(gA + (size_t)(t) * (16 * NB)), \
                                         (las_void*)&A2[pp][w4][0], 16, 0, 0); \
        __builtin_amdgcn_global_load_lds((gas_void*)(gB + (size_t)(t) * (16 * N1)), \
                                         (las_void*)&B2[pp][w4][0], 16, 0, 0); \
    }

    float acc[4][4];
#pragma unroll
    for (int r = 0; r < 4; ++r)
#pragma unroll
        for (int c = 0; c < 4; ++c) acc[r][c] = 0.f;

    // prologue
    STAGE(0, 0);
    asm volatile("s_waitcnt vmcnt(0)" ::: "memory");
    __builtin_amdgcn_s_barrier();
    __builtin_amdgcn_sched_barrier(0);

    int p = 0;
    for (int t = 0; t < NSTEP; ++t) {
        if (t + 1 < NSTEP) STAGE(p ^ 1, t + 1);
#pragma unroll
        for (int kk = 0; kk < 16; ++kk) {
            float4 av = *(const float4*)(&A2[p][kk][ty << 2]);
            float4 bv = *(const float4*)(&B2[p][kk][tx << 2]);
            acc[0][0] = fmaf(av.x, bv.x, acc[0][0]); acc[0][1] = fmaf(av.x, bv.y, acc[0][1]);
            acc[0][2] = fmaf(av.x, bv.z, acc[0][2]); acc[0][3] = fmaf(av.x, bv.w, acc[0][3]);
            acc[1][0] = fmaf(av.y, bv.x, acc[1][0]); acc[1][1] = fmaf(av.y, bv.y, acc[1][1]);
            acc[1][2] = fmaf(av.y, bv.z, acc[1][2]); acc[1][3] = fmaf(av.y, bv.w, acc[1][3]);
            acc[2][0] = fmaf(av.z, bv.x, acc[2][0]); acc[2][1] = fmaf(av.z, bv.y, acc[2][1]);
            acc[2][2] = fmaf(av.z, bv.z, acc[2][2]); acc[2][3] = fmaf(av.z, bv.w, acc[2][3]);
            acc[3][0] = fmaf(av.w, bv.x, acc[3][0]); acc[3][1] = fmaf(av.w, bv.y, acc[3][1]);
            acc[3][2] = fmaf(av.w, bv.z, acc[3][2]); acc[3][3] = fmaf(av.w, bv.w, acc[3][3]);
        }
        asm volatile("s_waitcnt vmcnt(0)" ::: "memory");
        __builtin_amdgcn_s_barrier();
        __builtin_amdgcn_sched_barrier(0);
        p ^= 1;
    }
#undef STAGE

    // LIF layer 1: exact per-step recurrence, spikes recorded as 64-bit mask.
    float c[16], v[16];
    u32 blo[16], bhi[16];
#pragma unroll
    for (int u = 0; u < 16; ++u) {
        c[u] = acc[u >> 2][u & 3];
        v[u] = 0.f; blo[u] = 0u; bhi[u] = 0u;
    }
    for (int t = 0; t < 32; ++t) {
#pragma unroll
        for (int u = 0; u < 16; ++u) {
            v[u] += (c[u] - v[u]) * 0.5f;           // v += (c - v)/tau, tau=2
            bool s = v[u] >= 1.0f;                  // spike(v - 1) == (v >= 1)
            blo[u] |= (s ? 1u : 0u) << t;
            v[u] = s ? 0.f : v[u];                  // hard reset
        }
    }
    for (int t = 0; t < 32; ++t) {
#pragma unroll
        for (int u = 0; u < 16; ++u) {
            v[u] += (c[u] - v[u]) * 0.5f;
            bool s = v[u] >= 1.0f;
            bhi[u] |= (s ? 1u : 0u) << t;
            v[u] = s ? 0.f : v[u];
        }
    }
#pragma unroll
    for (int u = 0; u < 16; ++u) {
        int r = u >> 2, cc = u & 3;
        bits[(size_t)(bm + (ty << 2) + r) * N1 + (bn + (tx << 2) + cc)] =
            ((u64)bhi[u] << 32) | (u64)blo[u];
    }
}

// ---------------- K3: sparse c2, 1 batch/block, 4 waves x 256-j segments ----------------
__global__ __launch_bounds__(256) void k_lif2(
    const u64* __restrict__ bits, const float* __restrict__ W2T,
    float* __restrict__ out)
{
    __shared__ u64  masksS[N1];         // 8 KB
    __shared__ u32  idxS[N1];           // 4 KB
    __shared__ float c2S[4][64][12];    // 12 KB (per-wave partials)
    __shared__ float s2S[64][10];       // 2.5 KB

    const int tid  = threadIdx.x;
    const int w    = tid >> 6;      // wave = j-segment
    const int lane = tid & 63;      // = timestep in phase 2
    const int b    = blockIdx.x;

    const u64* row = bits + (size_t)b * N1;
    const int base_j = w << 8;

    // ---- phase 1: each wave scans its 256-j segment, ballot-compacts ----
    int nact = 0;
#pragma unroll
    for (int it = 0; it < 4; ++it) {
        int j = base_j + (it << 6) + lane;
        u64 m = row[j];
        u64 ball = __ballot(m != 0ULL);
        int pos = nact + __popcll(ball & ((1ULL << lane) - 1ULL));
        if (m != 0ULL) { masksS[base_j + pos] = m; idxS[base_j + pos] = j; }
        nact += __popcll(ball);
    }

    // ---- phase 2: dense accumulation over this wave's active list; lane = t ----
    float acc[10];
#pragma unroll
    for (int i = 0; i < 10; ++i) acc[i] = 0.f;

#define LIF2_BODY(A)                                                      \
    {                                                                     \
        u64 m = masksS[(A)];                                              \
        int j = __builtin_amdgcn_readfirstlane((int)idxS[(A)]);           \
        float sf = (float)((m >> lane) & 1ULL);                           \
        const float* wr = W2T + j * 12;                                   \
        float4 w0 = *(const float4*)(wr);                                 \
        float4 w1 = *(const float4*)(wr + 4);                             \
        float2 w2 = *(const float2*)(wr + 8);                             \
        acc[0] += sf * w0.x; acc[1] += sf * w0.y;                         \
        acc[2] += sf * w0.z; acc[3] += sf * w0.w;                         \
        acc[4] += sf * w1.x; acc[5] += sf * w1.y;                         \
        acc[6] += sf * w1.z; acc[7] += sf * w1.w;                         \
        acc[8] += sf * w2.x; acc[9] += sf * w2.y;                         \
    }

    int a = 0;
    for (; a + 2 <= nact; a += 2) { LIF2_BODY(base_j + a); LIF2_BODY(base_j + a + 1); }
    if (a < nact) LIF2_BODY(base_j + a);
#undef LIF2_BODY

#pragma unroll
    for (int i = 0; i < 10; ++i) c2S[w][lane][i] = acc[i];
    __syncthreads();

    // ---- reduce 4 partials + LIF layer 2 (10 threads, serial over t) ----
    if (tid < 10) {
        const int i = tid;
        float v2 = 0.f;
        for (int t = 0; t < 64; ++t) {
            float cc = ((c2S[0][t][i] + c2S[1][t][i]) + c2S[2][t][i]) + c2S[3][t][i];
            v2 += (cc - v2) * 0.5f;
            bool s = v2 >= 1.0f;
            s2S[t][i] = s ? 1.f : 0.f;
            v2 = s ? 0.f : v2;
        }
    }
    __syncthreads();

    // ---- write out[t][b][0..9] ----
    for (int idx = tid; idx < 64 * 10; idx += 256) {
        int t = idx / 10, i = idx % 10;
        out[(size_t)t * (NB * N2) + (size_t)b * N2 + i] = s2S[t][i];
    }
}

extern "C" void kernel_launch(void* const* d_in, const int* in_sizes, int n_in,
                              void* d_out, int out_size, void* d_ws, size_t ws_size,
                              hipStream_t stream) {
    const float* X  = (const float*)d_in[0];   // [2048, 784]
    const float* W1 = (const float*)d_in[1];   // [1024, 784]
    const float* W2 = (const float*)d_in[2];   // [10, 1024]
    float* out = (float*)d_out;                // [64, 2048, 10]

    char* ws = (char*)d_ws;
    u64*   bits = (u64*)ws;                                   // 16 MiB
    float* W2T  = (float*)(ws + (size_t)NB * N1 * 8);         // 48 KiB
    float* Xt   = (float*)(ws + (size_t)NB * N1 * 8 + 65536); // 6.27 MiB
    float* W1t  = Xt + (size_t)KDIM * NB;                     // 3.14 MiB

    k_w2t<<<dim3((N1 + 255) / 256), dim3(256), 0, stream>>>(W2, W2T);
    k_transpose2<<<dim3(2400), dim3(256), 0, stream>>>(X, Xt, W1, W1t);

    dim3 g1(N1 / 64, NB / 64);   // (16, 32)
    k_gemm_lif1<<<g1, dim3(256), 0, stream>>>(Xt, W1t, bits);

    k_lif2<<<dim3(NB), dim3(256), 0, stream>>>(bits, W2T, out);
}